// Round 2
// baseline (76.146 us; speedup 1.0000x reference)
//
#include <hip/hip_runtime.h>

#define NHEADS 8
#define NPTS 4
#define EDIM 256
#define GRIDW 32
#define LTOK 1024  // 32*32
#define NTOK 4096  // 4 * 1024

// ---------------------------------------------------------------------------
// K1: logits GEMM.  logits[token][0..63] = q @ W_off + b_off
//                   logits[token][64..95] = q @ W_attn + b_attn
// 512 blocks x 8 tokens, 192 threads (3 waves):
//   wave0: off cols 0..63, tokens 0..3;  wave1: off cols, tokens 4..7
//   wave2: attn cols (lane&31), tokens (lane>>5)*4 ..
// ---------------------------------------------------------------------------
__global__ __launch_bounds__(192) void logits_kernel(
    const float* __restrict__ query,   // [NTOK,256]
    const float* __restrict__ W_off,   // [256,64]
    const float* __restrict__ b_off,   // [64]
    const float* __restrict__ W_attn,  // [256,32]
    const float* __restrict__ b_attn,  // [32]
    float* __restrict__ logits)        // [NTOK,96]
{
    const int tb = blockIdx.x * 8;
    const int tid = threadIdx.x;

    __shared__ float qs[8][260];   // pad to 260 floats (16B-aligned rows, bank-spread)

    // stage 8 q-rows (8*64 float4 units)
    for (int u = tid; u < 512; u += 192) {
        const int row = u >> 6;
        const int c4 = (u & 63) * 4;
        *(float4*)&qs[row][c4] = *(const float4*)&query[(tb + row) * EDIM + c4];
    }
    __syncthreads();

    int col, ncols, tok0;
    const float* W;
    const float* bptr;
    if (tid < 128) {
        col = tid & 63; ncols = 64; tok0 = (tid >> 6) * 4; W = W_off; bptr = b_off;
    } else {
        const int lane = tid - 128;
        col = lane & 31; ncols = 32; tok0 = (lane >> 5) * 4; W = W_attn; bptr = b_attn;
    }

    float acc[4] = {0.f, 0.f, 0.f, 0.f};
    for (int k = 0; k < EDIM; k += 4) {
        const float w0 = W[(k + 0) * ncols + col];
        const float w1 = W[(k + 1) * ncols + col];
        const float w2 = W[(k + 2) * ncols + col];
        const float w3 = W[(k + 3) * ncols + col];
        #pragma unroll
        for (int i = 0; i < 4; ++i) {
            const float4 q4 = *(const float4*)&qs[tok0 + i][k];
            float t = fmaf(q4.x, w0, acc[i]);
            t = fmaf(q4.y, w1, t);
            t = fmaf(q4.z, w2, t);
            acc[i] = fmaf(q4.w, w3, t);
        }
    }

    const float bb = bptr[col];
    const int obase = (tid < 128) ? col : (64 + col);
    #pragma unroll
    for (int i = 0; i < 4; ++i)
        logits[(tb + tok0 + i) * 96 + obase] = acc[i] + bb;
}

// ---------------------------------------------------------------------------
// K2: corners + bilinear gather.  One block (256 thr) per token.
// out1[token][e] = sum over 128 taps of  w_tap * query[row_tap][e]
// 4 waves x 32 taps, each tap = wave-wide float4 load of a 1KB row.
// ---------------------------------------------------------------------------
__global__ __launch_bounds__(256) void gather_kernel(
    const float* __restrict__ query,   // [NTOK,256]
    const float* __restrict__ refp,    // [NTOK,2]
    const float* __restrict__ logits,  // [NTOK,96]
    float* __restrict__ out1)          // [NTOK,256]
{
    const int token = blockIdx.x;
    const int n = token >> 10;
    const int tid = threadIdx.x;

    __shared__ float cw[NHEADS * NPTS * 4];
    __shared__ int   cidx[NHEADS * NPTS * 4];
    __shared__ float partial[4][256];

    if (tid < 32) {
        const int s = tid;            // s = h*NPTS + p
        const int h = s >> 2;
        const float* lg = &logits[token * 96];
        const float l0 = lg[64 + h * 4 + 0];
        const float l1 = lg[64 + h * 4 + 1];
        const float l2 = lg[64 + h * 4 + 2];
        const float l3 = lg[64 + h * 4 + 3];
        const float m  = fmaxf(fmaxf(l0, l1), fmaxf(l2, l3));
        const float denom = __expf(l0 - m) + __expf(l1 - m) + __expf(l2 - m) + __expf(l3 - m);
        const float aw = __expf(lg[64 + s] - m) / (denom * (float)NHEADS);

        const float rx = refp[token * 2 + 0];
        const float ry = refp[token * 2 + 1];
        const float x = (rx + lg[2 * s + 0]) * 32.0f - 0.5f;
        const float y = (ry + lg[2 * s + 1]) * 32.0f - 0.5f;
        const float x0f = floorf(x);
        const float y0f = floorf(y);
        const float wx = x - x0f;
        const float wy = y - y0f;
        const int x0 = (int)x0f;
        const int y0 = (int)y0f;

        const int xi[4] = { x0, x0 + 1, x0, x0 + 1 };
        const int yi[4] = { y0, y0, y0 + 1, y0 + 1 };
        const float wc[4] = { (1.f - wx) * (1.f - wy), wx * (1.f - wy),
                              (1.f - wx) * wy,         wx * wy };
        #pragma unroll
        for (int c = 0; c < 4; ++c) {
            const bool valid = (xi[c] >= 0) & (xi[c] < GRIDW) & (yi[c] >= 0) & (yi[c] < GRIDW);
            cw[s * 4 + c]   = valid ? (wc[c] * aw) : 0.f;
            cidx[s * 4 + c] = valid ? ((n * LTOK + yi[c] * GRIDW + xi[c]) * EDIM) : 0;
        }
    }
    __syncthreads();

    const int w = tid >> 6;
    const int lane = tid & 63;
    float4 acc = {0.f, 0.f, 0.f, 0.f};
    #pragma unroll 8
    for (int t = 0; t < 32; ++t) {
        const int s = w * 32 + t;
        const float wt = cw[s];
        const float4 v = *(const float4*)&query[cidx[s] + lane * 4];
        acc.x = fmaf(wt, v.x, acc.x);
        acc.y = fmaf(wt, v.y, acc.y);
        acc.z = fmaf(wt, v.z, acc.z);
        acc.w = fmaf(wt, v.w, acc.w);
    }
    *(float4*)&partial[w][lane * 4] = acc;
    __syncthreads();

    out1[token * EDIM + tid] =
        partial[0][tid] + partial[1][tid] + partial[2][tid] + partial[3][tid];
}

// ---------------------------------------------------------------------------
// K3: projection, in-place safe.  Block = 16 rows x all 256 cols.
// Thread (ty=tid>>6, tx=tid&63) computes 4 rows x 4 cols.
// A rows staged to LDS (barrier) before any write -> out may alias A.
// ---------------------------------------------------------------------------
__global__ __launch_bounds__(256) void proj_kernel(
    const float* __restrict__ A,      // [NTOK,256]  (aliases out)
    const float* __restrict__ W,      // [256,256]
    const float* __restrict__ b,      // [256]
    float* __restrict__ out)          // [NTOK,256]
{
    const int rb = blockIdx.x * 16;
    const int tid = threadIdx.x;
    const int tx = tid & 63;          // col group: cols tx*4 .. +3
    const int ty = tid >> 6;          // row group: rows ty*4 .. +3

    __shared__ float As[16][260];

    // stage 16 rows (16*64 float4 units)
    for (int u = tid; u < 1024; u += 256) {
        const int row = u >> 6;
        const int c4 = (u & 63) * 4;
        *(float4*)&As[row][c4] = *(const float4*)&A[(rb + row) * EDIM + c4];
    }
    __syncthreads();

    float acc[4][4] = {};
    const int c0 = tx * 4;
    for (int k = 0; k < EDIM; k += 4) {
        float4 a[4];
        #pragma unroll
        for (int i = 0; i < 4; ++i)
            a[i] = *(const float4*)&As[ty * 4 + i][k];   // wave-uniform broadcast
        const float4 w0 = *(const float4*)&W[(k + 0) * EDIM + c0];
        const float4 w1 = *(const float4*)&W[(k + 1) * EDIM + c0];
        const float4 w2 = *(const float4*)&W[(k + 2) * EDIM + c0];
        const float4 w3 = *(const float4*)&W[(k + 3) * EDIM + c0];
        #pragma unroll
        for (int i = 0; i < 4; ++i) {
            acc[i][0] = fmaf(a[i].x, w0.x, acc[i][0]);
            acc[i][1] = fmaf(a[i].x, w0.y, acc[i][1]);
            acc[i][2] = fmaf(a[i].x, w0.z, acc[i][2]);
            acc[i][3] = fmaf(a[i].x, w0.w, acc[i][3]);
            acc[i][0] = fmaf(a[i].y, w1.x, acc[i][0]);
            acc[i][1] = fmaf(a[i].y, w1.y, acc[i][1]);
            acc[i][2] = fmaf(a[i].y, w1.z, acc[i][2]);
            acc[i][3] = fmaf(a[i].y, w1.w, acc[i][3]);
            acc[i][0] = fmaf(a[i].z, w2.x, acc[i][0]);
            acc[i][1] = fmaf(a[i].z, w2.y, acc[i][1]);
            acc[i][2] = fmaf(a[i].z, w2.z, acc[i][2]);
            acc[i][3] = fmaf(a[i].z, w2.w, acc[i][3]);
            acc[i][0] = fmaf(a[i].w, w3.x, acc[i][0]);
            acc[i][1] = fmaf(a[i].w, w3.y, acc[i][1]);
            acc[i][2] = fmaf(a[i].w, w3.z, acc[i][2]);
            acc[i][3] = fmaf(a[i].w, w3.w, acc[i][3]);
        }
    }

    const float4 bias = *(const float4*)&b[c0];
    #pragma unroll
    for (int i = 0; i < 4; ++i) {
        float4 o;
        o.x = acc[i][0] + bias.x;
        o.y = acc[i][1] + bias.y;
        o.z = acc[i][2] + bias.z;
        o.w = acc[i][3] + bias.w;
        *(float4*)&out[(rb + ty * 4 + i) * EDIM + c0] = o;
    }
}

extern "C" void kernel_launch(void* const* d_in, const int* in_sizes, int n_in,
                              void* d_out, int out_size, void* d_ws, size_t ws_size,
                              hipStream_t stream) {
    const float* query  = (const float*)d_in[0];
    const float* refp   = (const float*)d_in[1];
    const float* W_off  = (const float*)d_in[2];
    const float* b_off  = (const float*)d_in[3];
    const float* W_attn = (const float*)d_in[4];
    const float* b_attn = (const float*)d_in[5];
    const float* W_out  = (const float*)d_in[6];
    const float* b_out  = (const float*)d_in[7];
    float* out = (float*)d_out;

    float* logits = (float*)d_ws;     // NTOK*96 f32 = 1.57 MB
    float* out1   = out;              // gather result lives in d_out; proj is in-place safe

    logits_kernel<<<NTOK / 8, 192, 0, stream>>>(query, W_off, b_off, W_attn, b_attn, logits);
    gather_kernel<<<NTOK, 256, 0, stream>>>(query, refp, logits, out1);
    proj_kernel<<<NTOK / 16, 256, 0, stream>>>(out1, W_out, b_out, out);
}

// Round 3
// 63.657 us; speedup vs baseline: 1.1962x; 1.1962x over previous
//
#include <hip/hip_runtime.h>

#define NHEADS 8
#define NPTS 4
#define EDIM 256
#define GRIDW 32
#define LTOK 1024  // 32*32
#define NTOK 4096  // 4 * 1024

// ---------------------------------------------------------------------------
// K1: logits GEMM.  logits[token][0..63] = q @ W_off + b_off
//                   logits[token][64..95] = q @ W_attn + b_attn
// 512 blocks x 8 tokens, 192 threads (3 waves).
// ---------------------------------------------------------------------------
__global__ __launch_bounds__(192) void logits_kernel(
    const float* __restrict__ query,   // [NTOK,256]
    const float* __restrict__ W_off,   // [256,64]
    const float* __restrict__ b_off,   // [64]
    const float* __restrict__ W_attn,  // [256,32]
    const float* __restrict__ b_attn,  // [32]
    float* __restrict__ logits)        // [NTOK,96]
{
    const int tb = blockIdx.x * 8;
    const int tid = threadIdx.x;

    __shared__ float qs[8][260];

    for (int u = tid; u < 512; u += 192) {
        const int row = u >> 6;
        const int c4 = (u & 63) * 4;
        *(float4*)&qs[row][c4] = *(const float4*)&query[(tb + row) * EDIM + c4];
    }
    __syncthreads();

    int col, ncols, tok0;
    const float* W;
    const float* bptr;
    if (tid < 128) {
        col = tid & 63; ncols = 64; tok0 = (tid >> 6) * 4; W = W_off; bptr = b_off;
    } else {
        const int lane = tid - 128;
        col = lane & 31; ncols = 32; tok0 = (lane >> 5) * 4; W = W_attn; bptr = b_attn;
    }

    float acc[4] = {0.f, 0.f, 0.f, 0.f};
    for (int k = 0; k < EDIM; k += 4) {
        const float w0 = W[(k + 0) * ncols + col];
        const float w1 = W[(k + 1) * ncols + col];
        const float w2 = W[(k + 2) * ncols + col];
        const float w3 = W[(k + 3) * ncols + col];
        #pragma unroll
        for (int i = 0; i < 4; ++i) {
            const float4 q4 = *(const float4*)&qs[tok0 + i][k];
            float t = fmaf(q4.x, w0, acc[i]);
            t = fmaf(q4.y, w1, t);
            t = fmaf(q4.z, w2, t);
            acc[i] = fmaf(q4.w, w3, t);
        }
    }

    const float bb = bptr[col];
    const int obase = (tid < 128) ? col : (64 + col);
    #pragma unroll
    for (int i = 0; i < 4; ++i)
        logits[(tb + tok0 + i) * 96 + obase] = acc[i] + bb;
}

// ---------------------------------------------------------------------------
// K2: corners + bilinear gather.  Wave-per-token: 4 tokens/block, 1024 blocks.
// out1[token][e] = sum over 128 taps of w_tap * query[row_tap][e]
// Each wave handles its token's 128 taps; tap = wave-wide float4 row load.
// ---------------------------------------------------------------------------
__global__ __launch_bounds__(256) void gather_kernel(
    const float* __restrict__ query,   // [NTOK,256]
    const float* __restrict__ refp,    // [NTOK,2]
    const float* __restrict__ logits,  // [NTOK,96]
    float* __restrict__ out1)          // [NTOK,256]
{
    const int tb = blockIdx.x * 4;
    const int tid = threadIdx.x;

    __shared__ float cwt[4][NHEADS * NPTS * 4];
    __shared__ int   cix[4][NHEADS * NPTS * 4];

    if (tid < 128) {
        const int t = tid >> 5;        // which of the 4 tokens
        const int s = tid & 31;        // s = h*NPTS + p
        const int token = tb + t;
        const int n = token >> 10;
        const int h = s >> 2;
        const float* lg = &logits[token * 96];
        const float l0 = lg[64 + h * 4 + 0];
        const float l1 = lg[64 + h * 4 + 1];
        const float l2 = lg[64 + h * 4 + 2];
        const float l3 = lg[64 + h * 4 + 3];
        const float m  = fmaxf(fmaxf(l0, l1), fmaxf(l2, l3));
        const float denom = __expf(l0 - m) + __expf(l1 - m) + __expf(l2 - m) + __expf(l3 - m);
        const float aw = __expf(lg[64 + s] - m) / (denom * (float)NHEADS);

        const float rx = refp[token * 2 + 0];
        const float ry = refp[token * 2 + 1];
        const float x = (rx + lg[2 * s + 0]) * 32.0f - 0.5f;
        const float y = (ry + lg[2 * s + 1]) * 32.0f - 0.5f;
        const float x0f = floorf(x);
        const float y0f = floorf(y);
        const float wx = x - x0f;
        const float wy = y - y0f;
        const int x0 = (int)x0f;
        const int y0 = (int)y0f;

        const int xi[4] = { x0, x0 + 1, x0, x0 + 1 };
        const int yi[4] = { y0, y0, y0 + 1, y0 + 1 };
        const float wc[4] = { (1.f - wx) * (1.f - wy), wx * (1.f - wy),
                              (1.f - wx) * wy,         wx * wy };
        #pragma unroll
        for (int c = 0; c < 4; ++c) {
            const bool valid = (xi[c] >= 0) & (xi[c] < GRIDW) & (yi[c] >= 0) & (yi[c] < GRIDW);
            cwt[t][s * 4 + c] = valid ? (wc[c] * aw) : 0.f;
            cix[t][s * 4 + c] = valid ? ((n * LTOK + yi[c] * GRIDW + xi[c]) * EDIM) : 0;
        }
    }
    __syncthreads();

    const int w = tid >> 6;            // wave -> token tb+w
    const int lane = tid & 63;
    const int loff = lane * 4;

    float4 acc = {0.f, 0.f, 0.f, 0.f};
    #pragma unroll 8
    for (int t = 0; t < 128; ++t) {
        const float wt = cwt[w][t];
        const float4 v = *(const float4*)&query[cix[w][t] + loff];
        acc.x = fmaf(wt, v.x, acc.x);
        acc.y = fmaf(wt, v.y, acc.y);
        acc.z = fmaf(wt, v.z, acc.z);
        acc.w = fmaf(wt, v.w, acc.w);
    }
    *(float4*)&out1[(tb + w) * EDIM + loff] = acc;
}

// ---------------------------------------------------------------------------
// K3: projection, in-place safe (row-owned blocks).
// 512 blocks x 8 rows x 256 cols; thread = 2 rows x 4 cols.
// ---------------------------------------------------------------------------
__global__ __launch_bounds__(256) void proj_kernel(
    const float* __restrict__ A,      // [NTOK,256]  (aliases out)
    const float* __restrict__ W,      // [256,256]
    const float* __restrict__ b,      // [256]
    float* __restrict__ out)          // [NTOK,256]
{
    const int rb = blockIdx.x * 8;
    const int tid = threadIdx.x;
    const int tx = tid & 63;          // col group: c0 = tx*4
    const int ty = tid >> 6;          // row group: rows ty*2, ty*2+1

    __shared__ float As[8][260];

    // stage 8 rows (8*64 float4 units)
    for (int u = tid; u < 512; u += 256) {
        const int row = u >> 6;
        const int c4 = (u & 63) * 4;
        *(float4*)&As[row][c4] = *(const float4*)&A[(rb + row) * EDIM + c4];
    }
    __syncthreads();

    float acc[2][4] = {};
    const int c0 = tx * 4;
    const int r0 = ty * 2;
    for (int k = 0; k < EDIM; k += 4) {
        float4 a0 = *(const float4*)&As[r0 + 0][k];
        float4 a1 = *(const float4*)&As[r0 + 1][k];
        const float4 w0 = *(const float4*)&W[(k + 0) * EDIM + c0];
        const float4 w1 = *(const float4*)&W[(k + 1) * EDIM + c0];
        const float4 w2 = *(const float4*)&W[(k + 2) * EDIM + c0];
        const float4 w3 = *(const float4*)&W[(k + 3) * EDIM + c0];

        acc[0][0] = fmaf(a0.x, w0.x, acc[0][0]);
        acc[0][1] = fmaf(a0.x, w0.y, acc[0][1]);
        acc[0][2] = fmaf(a0.x, w0.z, acc[0][2]);
        acc[0][3] = fmaf(a0.x, w0.w, acc[0][3]);
        acc[0][0] = fmaf(a0.y, w1.x, acc[0][0]);
        acc[0][1] = fmaf(a0.y, w1.y, acc[0][1]);
        acc[0][2] = fmaf(a0.y, w1.z, acc[0][2]);
        acc[0][3] = fmaf(a0.y, w1.w, acc[0][3]);
        acc[0][0] = fmaf(a0.z, w2.x, acc[0][0]);
        acc[0][1] = fmaf(a0.z, w2.y, acc[0][1]);
        acc[0][2] = fmaf(a0.z, w2.z, acc[0][2]);
        acc[0][3] = fmaf(a0.z, w2.w, acc[0][3]);
        acc[0][0] = fmaf(a0.w, w3.x, acc[0][0]);
        acc[0][1] = fmaf(a0.w, w3.y, acc[0][1]);
        acc[0][2] = fmaf(a0.w, w3.z, acc[0][2]);
        acc[0][3] = fmaf(a0.w, w3.w, acc[0][3]);

        acc[1][0] = fmaf(a1.x, w0.x, acc[1][0]);
        acc[1][1] = fmaf(a1.x, w0.y, acc[1][1]);
        acc[1][2] = fmaf(a1.x, w0.z, acc[1][2]);
        acc[1][3] = fmaf(a1.x, w0.w, acc[1][3]);
        acc[1][0] = fmaf(a1.y, w1.x, acc[1][0]);
        acc[1][1] = fmaf(a1.y, w1.y, acc[1][1]);
        acc[1][2] = fmaf(a1.y, w1.z, acc[1][2]);
        acc[1][3] = fmaf(a1.y, w1.w, acc[1][3]);
        acc[1][0] = fmaf(a1.z, w2.x, acc[1][0]);
        acc[1][1] = fmaf(a1.z, w2.y, acc[1][1]);
        acc[1][2] = fmaf(a1.z, w2.z, acc[1][2]);
        acc[1][3] = fmaf(a1.z, w2.w, acc[1][3]);
        acc[1][0] = fmaf(a1.w, w3.x, acc[1][0]);
        acc[1][1] = fmaf(a1.w, w3.y, acc[1][1]);
        acc[1][2] = fmaf(a1.w, w3.z, acc[1][2]);
        acc[1][3] = fmaf(a1.w, w3.w, acc[1][3]);
    }

    const float4 bias = *(const float4*)&b[c0];
    #pragma unroll
    for (int i = 0; i < 2; ++i) {
        float4 o;
        o.x = acc[i][0] + bias.x;
        o.y = acc[i][1] + bias.y;
        o.z = acc[i][2] + bias.z;
        o.w = acc[i][3] + bias.w;
        *(float4*)&out[(rb + r0 + i) * EDIM + c0] = o;
    }
}

extern "C" void kernel_launch(void* const* d_in, const int* in_sizes, int n_in,
                              void* d_out, int out_size, void* d_ws, size_t ws_size,
                              hipStream_t stream) {
    const float* query  = (const float*)d_in[0];
    const float* refp   = (const float*)d_in[1];
    const float* W_off  = (const float*)d_in[2];
    const float* b_off  = (const float*)d_in[3];
    const float* W_attn = (const float*)d_in[4];
    const float* b_attn = (const float*)d_in[5];
    const float* W_out  = (const float*)d_in[6];
    const float* b_out  = (const float*)d_in[7];
    float* out = (float*)d_out;

    float* logits = (float*)d_ws;     // NTOK*96 f32 = 1.57 MB
    float* out1   = out;              // gather result in d_out; proj is in-place safe (row-owned)

    logits_kernel<<<NTOK / 8, 192, 0, stream>>>(query, W_off, b_off, W_attn, b_attn, logits);
    gather_kernel<<<NTOK / 4, 256, 0, stream>>>(query, refp, logits, out1);
    proj_kernel<<<NTOK / 8, 256, 0, stream>>>(out1, W_out, b_out, out);
}

// Round 4
// 51.760 us; speedup vs baseline: 1.4711x; 1.2299x over previous
//
#include <hip/hip_runtime.h>

#define NHEADS 8
#define NPTS 4
#define EDIM 256
#define GRIDW 32
#define LTOK 1024  // 32*32
#define NTOK 4096  // 4 * 1024

// ---------------------------------------------------------------------------
// K1 (fused): logits GEMV + softmax/corners + bilinear gather.
// 512 blocks x 8 tokens x 512 threads (8 waves).
//   phase 1: stage 8 q-rows to LDS
//   phase 2: GEMV  (wave w -> token w, lane -> W_off col; half block -> W_attn)
//   phase 3: softmax + corner weights/indices (256 threads = 8 tok x 32 s)
//   phase 4: gather (wave w -> token w, 128 taps, scalar-base row loads)
// ---------------------------------------------------------------------------
__global__ __launch_bounds__(512) void fused_sample_kernel(
    const float* __restrict__ query,   // [NTOK,256]
    const float* __restrict__ refp,    // [NTOK,2]
    const float* __restrict__ W_off,   // [256,64]
    const float* __restrict__ b_off,   // [64]
    const float* __restrict__ W_attn,  // [256,32]
    const float* __restrict__ b_attn,  // [32]
    float* __restrict__ out1)          // [NTOK,256]
{
    const int tb = blockIdx.x * 8;
    const int tid = threadIdx.x;

    __shared__ float qs[8][260];
    __shared__ float lg[8][96];
    __shared__ float cw[8][128];
    __shared__ int   ci[8][128];

    // ---- phase 1: stage 8 q-rows (512 float4 units, one per thread) ----
    {
        const int row = tid >> 6;
        const int c4 = (tid & 63) * 4;
        *(float4*)&qs[row][c4] = *(const float4*)&query[(tb + row) * EDIM + c4];
    }
    __syncthreads();

    // ---- phase 2a: offsets GEMV. wave w -> token w, lane -> col ----
    {
        const int token = tid >> 6;
        const int col = tid & 63;
        float a0 = 0.f, a1 = 0.f, a2 = 0.f, a3 = 0.f;
        #pragma unroll 4
        for (int k = 0; k < EDIM; k += 4) {
            const float4 q4 = *(const float4*)&qs[token][k];
            a0 = fmaf(q4.x, W_off[(k + 0) * 64 + col], a0);
            a1 = fmaf(q4.y, W_off[(k + 1) * 64 + col], a1);
            a2 = fmaf(q4.z, W_off[(k + 2) * 64 + col], a2);
            a3 = fmaf(q4.w, W_off[(k + 3) * 64 + col], a3);
        }
        lg[token][col] = (a0 + a1) + (a2 + a3) + b_off[col];
    }
    // ---- phase 2b: attn GEMV. threads 0..255: token = tid>>5, col = tid&31 ----
    if (tid < 256) {
        const int token = tid >> 5;
        const int col = tid & 31;
        float a0 = 0.f, a1 = 0.f, a2 = 0.f, a3 = 0.f;
        #pragma unroll 4
        for (int k = 0; k < EDIM; k += 4) {
            const float4 q4 = *(const float4*)&qs[token][k];
            a0 = fmaf(q4.x, W_attn[(k + 0) * 32 + col], a0);
            a1 = fmaf(q4.y, W_attn[(k + 1) * 32 + col], a1);
            a2 = fmaf(q4.z, W_attn[(k + 2) * 32 + col], a2);
            a3 = fmaf(q4.w, W_attn[(k + 3) * 32 + col], a3);
        }
        lg[token][64 + col] = (a0 + a1) + (a2 + a3) + b_attn[col];
    }
    __syncthreads();

    // ---- phase 3: softmax + corners. threads 0..255 ----
    if (tid < 256) {
        const int t = tid >> 5;        // local token
        const int s = tid & 31;        // s = h*NPTS + p
        const int token = tb + t;
        const int n = token >> 10;
        const int h = s >> 2;
        const float l0 = lg[t][64 + h * 4 + 0];
        const float l1 = lg[t][64 + h * 4 + 1];
        const float l2 = lg[t][64 + h * 4 + 2];
        const float l3 = lg[t][64 + h * 4 + 3];
        const float m  = fmaxf(fmaxf(l0, l1), fmaxf(l2, l3));
        const float denom = __expf(l0 - m) + __expf(l1 - m) + __expf(l2 - m) + __expf(l3 - m);
        const float aw = __expf(lg[t][64 + s] - m) / (denom * (float)NHEADS);

        const float rx = refp[token * 2 + 0];
        const float ry = refp[token * 2 + 1];
        const float x = (rx + lg[t][2 * s + 0]) * 32.0f - 0.5f;
        const float y = (ry + lg[t][2 * s + 1]) * 32.0f - 0.5f;
        const float x0f = floorf(x);
        const float y0f = floorf(y);
        const float wx = x - x0f;
        const float wy = y - y0f;
        const int x0 = (int)x0f;
        const int y0 = (int)y0f;

        const int xi[4] = { x0, x0 + 1, x0, x0 + 1 };
        const int yi[4] = { y0, y0, y0 + 1, y0 + 1 };
        const float wc[4] = { (1.f - wx) * (1.f - wy), wx * (1.f - wy),
                              (1.f - wx) * wy,         wx * wy };
        #pragma unroll
        for (int c = 0; c < 4; ++c) {
            const bool valid = (xi[c] >= 0) & (xi[c] < GRIDW) & (yi[c] >= 0) & (yi[c] < GRIDW);
            cw[t][s * 4 + c] = valid ? (wc[c] * aw) : 0.f;
            ci[t][s * 4 + c] = valid ? ((n * LTOK + yi[c] * GRIDW + xi[c]) * EDIM) : 0;
        }
    }
    __syncthreads();

    // ---- phase 4: gather. wave w -> token tb+w, 128 taps ----
    const int w = tid >> 6;
    const int lane = tid & 63;
    const int loff = lane * 4;

    float4 acc = {0.f, 0.f, 0.f, 0.f};
    #pragma unroll 8
    for (int t = 0; t < 128; ++t) {
        // row index & weight are wave-uniform: move to scalar regs so the
        // load becomes global_load_dwordx4 v, v_loff, s[base] (scalar-pipe
        // address math) and the fma takes the weight as an SGPR operand.
        const int sidx = __builtin_amdgcn_readfirstlane(ci[w][t]);
        const float wt = __uint_as_float(
            (unsigned)__builtin_amdgcn_readfirstlane((int)__float_as_uint(cw[w][t])));
        const float4 v = *(const float4*)&query[sidx + loff];
        acc.x = fmaf(wt, v.x, acc.x);
        acc.y = fmaf(wt, v.y, acc.y);
        acc.z = fmaf(wt, v.z, acc.z);
        acc.w = fmaf(wt, v.w, acc.w);
    }
    *(float4*)&out1[(tb + w) * EDIM + loff] = acc;
}

// ---------------------------------------------------------------------------
// K2: projection, in-place safe (row-owned blocks).
// 512 blocks x 8 rows x 256 cols; thread = 2 rows x 4 cols; k unrolled x8.
// ---------------------------------------------------------------------------
__global__ __launch_bounds__(256) void proj_kernel(
    const float* __restrict__ A,      // [NTOK,256]  (aliases out)
    const float* __restrict__ W,      // [256,256]
    const float* __restrict__ b,      // [256]
    float* __restrict__ out)          // [NTOK,256]
{
    const int rb = blockIdx.x * 8;
    const int tid = threadIdx.x;
    const int tx = tid & 63;          // col group: c0 = tx*4
    const int ty = tid >> 6;          // row group: rows ty*2, ty*2+1

    __shared__ float As[8][260];

    for (int u = tid; u < 512; u += 256) {
        const int row = u >> 6;
        const int c4 = (u & 63) * 4;
        *(float4*)&As[row][c4] = *(const float4*)&A[(rb + row) * EDIM + c4];
    }
    __syncthreads();

    float4 accA = {0.f, 0.f, 0.f, 0.f};
    float4 accB = {0.f, 0.f, 0.f, 0.f};
    const int c0 = tx * 4;
    const int r0 = ty * 2;

#define STEP(a0v, a1v, wv)                    \
    accA.x = fmaf(a0v, wv.x, accA.x);         \
    accA.y = fmaf(a0v, wv.y, accA.y);         \
    accA.z = fmaf(a0v, wv.z, accA.z);         \
    accA.w = fmaf(a0v, wv.w, accA.w);         \
    accB.x = fmaf(a1v, wv.x, accB.x);         \
    accB.y = fmaf(a1v, wv.y, accB.y);         \
    accB.z = fmaf(a1v, wv.z, accB.z);         \
    accB.w = fmaf(a1v, wv.w, accB.w);

    for (int k = 0; k < EDIM; k += 8) {
        // 8 independent W row-loads in flight
        const float4 w0 = *(const float4*)&W[(k + 0) * EDIM + c0];
        const float4 w1 = *(const float4*)&W[(k + 1) * EDIM + c0];
        const float4 w2 = *(const float4*)&W[(k + 2) * EDIM + c0];
        const float4 w3 = *(const float4*)&W[(k + 3) * EDIM + c0];
        const float4 w4 = *(const float4*)&W[(k + 4) * EDIM + c0];
        const float4 w5 = *(const float4*)&W[(k + 5) * EDIM + c0];
        const float4 w6 = *(const float4*)&W[(k + 6) * EDIM + c0];
        const float4 w7 = *(const float4*)&W[(k + 7) * EDIM + c0];

        const float4 a0a = *(const float4*)&As[r0 + 0][k];
        const float4 a0b = *(const float4*)&As[r0 + 0][k + 4];
        const float4 a1a = *(const float4*)&As[r0 + 1][k];
        const float4 a1b = *(const float4*)&As[r0 + 1][k + 4];

        STEP(a0a.x, a1a.x, w0)
        STEP(a0a.y, a1a.y, w1)
        STEP(a0a.z, a1a.z, w2)
        STEP(a0a.w, a1a.w, w3)
        STEP(a0b.x, a1b.x, w4)
        STEP(a0b.y, a1b.y, w5)
        STEP(a0b.z, a1b.z, w6)
        STEP(a0b.w, a1b.w, w7)
    }
#undef STEP

    const float4 bias = *(const float4*)&b[c0];
    float4 o0, o1;
    o0.x = accA.x + bias.x; o0.y = accA.y + bias.y;
    o0.z = accA.z + bias.z; o0.w = accA.w + bias.w;
    o1.x = accB.x + bias.x; o1.y = accB.y + bias.y;
    o1.z = accB.z + bias.z; o1.w = accB.w + bias.w;
    *(float4*)&out[(rb + r0 + 0) * EDIM + c0] = o0;
    *(float4*)&out[(rb + r0 + 1) * EDIM + c0] = o1;
}

extern "C" void kernel_launch(void* const* d_in, const int* in_sizes, int n_in,
                              void* d_out, int out_size, void* d_ws, size_t ws_size,
                              hipStream_t stream) {
    const float* query  = (const float*)d_in[0];
    const float* refp   = (const float*)d_in[1];
    const float* W_off  = (const float*)d_in[2];
    const float* b_off  = (const float*)d_in[3];
    const float* W_attn = (const float*)d_in[4];
    const float* b_attn = (const float*)d_in[5];
    const float* W_out  = (const float*)d_in[6];
    const float* b_out  = (const float*)d_in[7];
    float* out = (float*)d_out;

    float* out1 = out;   // gather result in d_out; proj is in-place safe (row-owned)

    fused_sample_kernel<<<NTOK / 8, 512, 0, stream>>>(query, refp, W_off, b_off,
                                                      W_attn, b_attn, out1);
    proj_kernel<<<NTOK / 8, 256, 0, stream>>>(out1, W_out, b_out, out);
}

// Round 5
// 37.904 us; speedup vs baseline: 2.0089x; 1.3655x over previous
//
#include <hip/hip_runtime.h>

#define NHEADS 8
#define NPTS 4
#define EDIM 256
#define GRIDW 32
#define LTOK 1024  // 32*32
#define NTOK 4096  // 4 * 1024

// ---------------------------------------------------------------------------
// Fully fused kernel: 512 blocks x 8 tokens x 512 threads (8 waves).
//  P1: stage 8 q-rows to LDS
//  P2a: offsets GEMV, k-sliced (wave=k-slice, lane=col; W delivered once/block)
//  P2b: attn GEMV, k-sliced
//  P3: softmax + corner weights/indices
//  P4: bilinear gather (wave=token, 128 taps, scalar-base row loads) -> LDS
//  P5: projection, k-split: thread=(col, k-half), 8 rows/thread (W once/block)
//  P6: combine k-halves + bias, store
// ---------------------------------------------------------------------------
__global__ __launch_bounds__(512) void fused_all_kernel(
    const float* __restrict__ query,   // [NTOK,256]
    const float* __restrict__ refp,    // [NTOK,2]
    const float* __restrict__ W_off,   // [256,64]
    const float* __restrict__ b_off,   // [64]
    const float* __restrict__ W_attn,  // [256,32]
    const float* __restrict__ b_attn,  // [32]
    const float* __restrict__ W_outp,  // [256,256]
    const float* __restrict__ b_out,   // [256]
    float* __restrict__ out)           // [NTOK,256]
{
    const int tb = blockIdx.x * 8;
    const int tid = threadIdx.x;

    __shared__ float qs[8][260];        // q rows; reused as gathered rows (os) in P4+
    __shared__ float lg[8][96];         // logits
    __shared__ float cw[8][128];        // corner weights
    __shared__ int   ci[8][128];        // corner row base offsets
    __shared__ float ps[4096];          // 16KB partial-sum scratch (P2a/P2b/P6)

    // ---- P1: stage 8 q-rows (512 float4 units, one per thread) ----
    {
        const int row = tid >> 6;
        const int c4 = (tid & 63) * 4;
        *(float4*)&qs[row][c4] = *(const float4*)&query[(tb + row) * EDIM + c4];
    }
    __syncthreads();

    // ---- P2a: offsets GEMV, k-sliced. wave = k-slice (32 k), lane = col ----
    {
        const int ks = tid >> 6;          // 0..7
        const int col = tid & 63;
        const int kbase = ks * 32;
        float a[8] = {};
        #pragma unroll 2
        for (int kk = 0; kk < 32; kk += 4) {
            const int k = kbase + kk;
            const float w0 = W_off[(k + 0) * 64 + col];
            const float w1 = W_off[(k + 1) * 64 + col];
            const float w2 = W_off[(k + 2) * 64 + col];
            const float w3 = W_off[(k + 3) * 64 + col];
            #pragma unroll
            for (int t = 0; t < 8; ++t) {
                const float4 q4 = *(const float4*)&qs[t][k];   // LDS broadcast
                a[t] = fmaf(q4.x, w0, a[t]);
                a[t] = fmaf(q4.y, w1, a[t]);
                a[t] = fmaf(q4.z, w2, a[t]);
                a[t] = fmaf(q4.w, w3, a[t]);
            }
        }
        #pragma unroll
        for (int t = 0; t < 8; ++t) ps[(ks * 8 + t) * 64 + col] = a[t];
    }
    __syncthreads();
    {   // reduce 8 k-slices -> lg[t][col]
        const int t = tid >> 6;
        const int col = tid & 63;
        float s = b_off[col];
        #pragma unroll
        for (int k = 0; k < 8; ++k) s += ps[(k * 8 + t) * 64 + col];
        lg[t][col] = s;
    }
    __syncthreads();

    // ---- P2b: attn GEMV, k-sliced. 16 slices x 16 k, lane = col (32) ----
    {
        const int ks = tid >> 5;          // 0..15
        const int col = tid & 31;
        const int kbase = ks * 16;
        float a[8] = {};
        #pragma unroll
        for (int kk = 0; kk < 16; kk += 4) {
            const int k = kbase + kk;
            const float w0 = W_attn[(k + 0) * 32 + col];
            const float w1 = W_attn[(k + 1) * 32 + col];
            const float w2 = W_attn[(k + 2) * 32 + col];
            const float w3 = W_attn[(k + 3) * 32 + col];
            #pragma unroll
            for (int t = 0; t < 8; ++t) {
                const float4 q4 = *(const float4*)&qs[t][k];
                a[t] = fmaf(q4.x, w0, a[t]);
                a[t] = fmaf(q4.y, w1, a[t]);
                a[t] = fmaf(q4.z, w2, a[t]);
                a[t] = fmaf(q4.w, w3, a[t]);
            }
        }
        #pragma unroll
        for (int t = 0; t < 8; ++t) ps[(ks * 8 + t) * 32 + col] = a[t];
    }
    __syncthreads();
    if (tid < 256) {   // reduce 16 k-slices -> lg[t][64+col]
        const int t = tid >> 5;
        const int col = tid & 31;
        float s = b_attn[col];
        #pragma unroll
        for (int k = 0; k < 16; ++k) s += ps[(k * 8 + t) * 32 + col];
        lg[t][64 + col] = s;
    }
    __syncthreads();

    // ---- P3: softmax + corners. threads 0..255 = 8 tok x 32 samples ----
    if (tid < 256) {
        const int t = tid >> 5;
        const int s = tid & 31;           // s = h*NPTS + p
        const int token = tb + t;
        const int n = token >> 10;
        const int h = s >> 2;
        const float l0 = lg[t][64 + h * 4 + 0];
        const float l1 = lg[t][64 + h * 4 + 1];
        const float l2 = lg[t][64 + h * 4 + 2];
        const float l3 = lg[t][64 + h * 4 + 3];
        const float m  = fmaxf(fmaxf(l0, l1), fmaxf(l2, l3));
        const float denom = __expf(l0 - m) + __expf(l1 - m) + __expf(l2 - m) + __expf(l3 - m);
        const float aw = __expf(lg[t][64 + s] - m) / (denom * (float)NHEADS);

        const float rx = refp[token * 2 + 0];
        const float ry = refp[token * 2 + 1];
        const float x = (rx + lg[t][2 * s + 0]) * 32.0f - 0.5f;
        const float y = (ry + lg[t][2 * s + 1]) * 32.0f - 0.5f;
        const float x0f = floorf(x);
        const float y0f = floorf(y);
        const float wx = x - x0f;
        const float wy = y - y0f;
        const int x0 = (int)x0f;
        const int y0 = (int)y0f;

        const int xi[4] = { x0, x0 + 1, x0, x0 + 1 };
        const int yi[4] = { y0, y0, y0 + 1, y0 + 1 };
        const float wc[4] = { (1.f - wx) * (1.f - wy), wx * (1.f - wy),
                              (1.f - wx) * wy,         wx * wy };
        #pragma unroll
        for (int c = 0; c < 4; ++c) {
            const bool valid = (xi[c] >= 0) & (xi[c] < GRIDW) & (yi[c] >= 0) & (yi[c] < GRIDW);
            cw[t][s * 4 + c] = valid ? (wc[c] * aw) : 0.f;
            ci[t][s * 4 + c] = valid ? ((n * LTOK + yi[c] * GRIDW + xi[c]) * EDIM) : 0;
        }
    }
    __syncthreads();

    // ---- P4: gather. wave w -> token tb+w, 128 taps. Result -> qs (as os). ----
    {
        const int w = tid >> 6;
        const int lane = tid & 63;
        const int loff = lane * 4;

        float4 acc = {0.f, 0.f, 0.f, 0.f};
        #pragma unroll 8
        for (int t = 0; t < 128; ++t) {
            const int sidx = __builtin_amdgcn_readfirstlane(ci[w][t]);
            const float wt = __uint_as_float(
                (unsigned)__builtin_amdgcn_readfirstlane((int)__float_as_uint(cw[w][t])));
            const float4 v = *(const float4*)&query[sidx + loff];
            acc.x = fmaf(wt, v.x, acc.x);
            acc.y = fmaf(wt, v.y, acc.y);
            acc.z = fmaf(wt, v.z, acc.z);
            acc.w = fmaf(wt, v.w, acc.w);
        }
        *(float4*)&qs[w][loff] = acc;     // os[w] (qs no longer needed)
    }
    __syncthreads();

    // ---- P5: projection. thread = (col pc, k-half kh); 8 rows per thread ----
    const int pc = tid & 255;
    const int kh = tid >> 8;              // 0 or 1
    float pacc[8] = {};
    {
        const int kbase = kh * 128;
        #pragma unroll 2
        for (int kk = 0; kk < 128; kk += 4) {
            const int k = kbase + kk;
            const float w0 = W_outp[(k + 0) * EDIM + pc];
            const float w1 = W_outp[(k + 1) * EDIM + pc];
            const float w2 = W_outp[(k + 2) * EDIM + pc];
            const float w3 = W_outp[(k + 3) * EDIM + pc];
            #pragma unroll
            for (int r = 0; r < 8; ++r) {
                const float4 a4 = *(const float4*)&qs[r][k];   // LDS broadcast
                pacc[r] = fmaf(a4.x, w0, pacc[r]);
                pacc[r] = fmaf(a4.y, w1, pacc[r]);
                pacc[r] = fmaf(a4.z, w2, pacc[r]);
                pacc[r] = fmaf(a4.w, w3, pacc[r]);
            }
        }
    }
    if (kh == 1) {
        #pragma unroll
        for (int r = 0; r < 8; ++r) ps[r * 256 + pc] = pacc[r];
    }
    __syncthreads();

    // ---- P6: combine + bias + store (coalesced dword per wave) ----
    if (kh == 0) {
        const float bb = b_out[pc];
        #pragma unroll
        for (int r = 0; r < 8; ++r)
            out[(tb + r) * EDIM + pc] = pacc[r] + ps[r * 256 + pc] + bb;
    }
}

extern "C" void kernel_launch(void* const* d_in, const int* in_sizes, int n_in,
                              void* d_out, int out_size, void* d_ws, size_t ws_size,
                              hipStream_t stream) {
    const float* query  = (const float*)d_in[0];
    const float* refp   = (const float*)d_in[1];
    const float* W_off  = (const float*)d_in[2];
    const float* b_off  = (const float*)d_in[3];
    const float* W_attn = (const float*)d_in[4];
    const float* b_attn = (const float*)d_in[5];
    const float* W_out  = (const float*)d_in[6];
    const float* b_out  = (const float*)d_in[7];
    float* out = (float*)d_out;

    fused_all_kernel<<<NTOK / 8, 512, 0, stream>>>(query, refp, W_off, b_off,
                                                   W_attn, b_attn, W_out, b_out, out);
}